// Round 1
// baseline (180.131 us; speedup 1.0000x reference)
//
#include <hip/hip_runtime.h>

// Problem constants (from reference): B=4, N=100000, C=500, H=W=512.
#define B_DIM 4
#define N_DIM 100000
#define C_DIM 500
#define IMG_W 512.0f
#define IMG_H 512.0f

// C_DIM/4 float4 per classification row (500/4 = 125, exact)
#define ROW_VEC4 (C_DIM / 4)

__global__ __launch_bounds__(256) void InferenceTransform_66202625900988_kernel(
    const float* __restrict__ cls,       // [B,N,C]
    const float* __restrict__ reg,       // [B,N,4]
    const float* __restrict__ anchors,   // [1,N,4]
    const float* __restrict__ thresh_p,  // [1]
    const float* __restrict__ rfac,      // [4]
    float* __restrict__ out,             // boxes[B*N*4] | cls[B*N] | scores[B*N] | mask[B*N]
    int totalRows)
{
    const int lane          = threadIdx.x & 63;
    const int waveInBlock   = threadIdx.x >> 6;
    const int wavesPerBlock = blockDim.x >> 6;
    const int waveId        = blockIdx.x * wavesPerBlock + waveInBlock;
    const int nWaves        = gridDim.x * wavesPerBlock;

    const float thresh = thresh_p[0];
    const float rf0 = rfac[0], rf1 = rfac[1], rf2 = rfac[2], rf3 = rfac[3];

    float*       outBoxes = out;
    float*       outCls   = out + (size_t)B_DIM * N_DIM * 4;
    float*       outScore = outCls + (size_t)B_DIM * N_DIM;
    float*       outMask  = outScore + (size_t)B_DIM * N_DIM;

    for (int row = waveId; row < totalRows; row += nWaves) {
        const float4* rowp = (const float4*)(cls + (size_t)row * C_DIM);

        // Per-lane running max + argmax (strict > keeps first occurrence).
        float best = -1.0f;  // scores are uniform in [0,1)
        int   bidx = 0;
        #pragma unroll
        for (int it = 0; it < 2; ++it) {
            int v = lane + it * 64;
            if (v < ROW_VEC4) {
                float4 q = rowp[v];
                float vals[4] = {q.x, q.y, q.z, q.w};
                #pragma unroll
                for (int j = 0; j < 4; ++j) {
                    if (vals[j] > best) { best = vals[j]; bidx = v * 4 + j; }
                }
            }
        }

        // Wave-64 butterfly reduction carrying (val, idx), lower index wins ties.
        #pragma unroll
        for (int off = 32; off > 0; off >>= 1) {
            float ov = __shfl_xor(best, off, 64);
            int   oi = __shfl_xor(bidx, off, 64);
            if (ov > best || (ov == best && oi < bidx)) { best = ov; bidx = oi; }
        }

        if (lane == 0) {
            const int n = row % N_DIM;           // row = b*N + n
            float4 a = ((const float4*)anchors)[n];
            float4 r = ((const float4*)reg)[row];

            float width  = a.z - a.x;
            float height = a.w - a.y;
            float ctrx   = a.x + 0.5f * width;
            float ctry   = a.y + 0.5f * height;

            float dx = r.x * rf0;
            float dy = r.y * rf1;
            float dw = r.z * rf2;
            float dh = r.w * rf3;

            float px = ctrx + dx * width;
            float py = ctry + dy * height;
            float pw = expf(dw) * width;
            float ph = expf(dh) * height;

            float x1 = px - 0.5f * pw;
            float y1 = py - 0.5f * ph;
            float x2 = px + 0.5f * pw;
            float y2 = py + 0.5f * ph;

            x1 = fminf(fmaxf(x1, 0.0f), IMG_W);
            x2 = fminf(fmaxf(x2, 0.0f), IMG_W);
            y1 = fminf(fmaxf(y1, 0.0f), IMG_H);
            y2 = fminf(fmaxf(y2, 0.0f), IMG_H);

            const float m = (best > thresh) ? 1.0f : 0.0f;

            float4 box;
            box.x = x1 * m; box.y = y1 * m; box.z = x2 * m; box.w = y2 * m;
            ((float4*)outBoxes)[row] = box;
            outCls[row]   = (m != 0.0f) ? (float)bidx : 0.0f;
            outScore[row] = best * m;
            outMask[row]  = m;
        }
    }
}

extern "C" void kernel_launch(void* const* d_in, const int* in_sizes, int n_in,
                              void* d_out, int out_size, void* d_ws, size_t ws_size,
                              hipStream_t stream) {
    // Input order per setup_inputs(): imgs, classifications, regressions,
    // anchors, cls_thresh, regress_factor.
    const float* cls     = (const float*)d_in[1];
    const float* reg     = (const float*)d_in[2];
    const float* anchors = (const float*)d_in[3];
    const float* thresh  = (const float*)d_in[4];
    const float* rfac    = (const float*)d_in[5];
    float* out = (float*)d_out;

    const int totalRows = B_DIM * N_DIM;        // 400000
    const int block = 256;                       // 4 waves/block
    const int grid  = 2048;                      // 8 blocks/CU, grid-stride

    InferenceTransform_66202625900988_kernel<<<grid, block, 0, stream>>>(
        cls, reg, anchors, thresh, rfac, out, totalRows);
}

// Round 3
// 159.550 us; speedup vs baseline: 1.1290x; 1.1290x over previous
//
#include <hip/hip_runtime.h>

// Problem constants (from reference): B=4, N=100000, C=500, H=W=512.
#define B_DIM 4
#define N_DIM 100000
#define C_DIM 500
#define TOTAL_ROWS (B_DIM * N_DIM)
#define IMG_W 512.0f
#define IMG_H 512.0f

// Native clang vector type: accepted by __builtin_nontemporal_load.
typedef float floatx4 __attribute__((ext_vector_type(4)));

// 500 floats = 125 float4 per row. Lane l covers vec l (chunk 0) and vec l+64
// (chunk 1, only lanes 0..60). Global idx = 4*(lane + 64*chunk) + j, which is
// monotonic in lane within a chunk -> ballot-based argmax tie-break is exact.

__device__ __forceinline__ void scan4(floatx4 q, int i0, float& best, int& bidx) {
    if (q.x > best) { best = q.x; bidx = i0;     }
    if (q.y > best) { best = q.y; bidx = i0 + 1; }
    if (q.z > best) { best = q.z; bidx = i0 + 2; }
    if (q.w > best) { best = q.w; bidx = i0 + 3; }
}

__global__ __launch_bounds__(256) void InferenceTransform_66202625900988_kernel(
    const float* __restrict__ cls,       // [B,N,C]
    const float* __restrict__ reg,       // [B,N,4]
    const float* __restrict__ anchors,   // [1,N,4]
    const float* __restrict__ thresh_p,  // [1]
    const float* __restrict__ rfac,      // [4]
    float* __restrict__ out)             // boxes[B*N*4] | cls[B*N] | scores[B*N] | mask[B*N]
{
    const int lane          = threadIdx.x & 63;
    const int waveInBlock   = threadIdx.x >> 6;
    const int wavesPerBlock = blockDim.x >> 6;
    const int waveId        = blockIdx.x * wavesPerBlock + waveInBlock;
    const int nWaves        = gridDim.x * wavesPerBlock;

    const float thresh = thresh_p[0];
    const float rf0 = rfac[0], rf1 = rfac[1], rf2 = rfac[2], rf3 = rfac[3];

    float*       outBoxes = out;
    float*       outCls   = out + (size_t)TOTAL_ROWS * 4;
    float*       outScore = outCls + (size_t)TOTAL_ROWS;
    float*       outMask  = outScore + (size_t)TOTAL_ROWS;

    const bool tail = lane < (C_DIM / 4 - 64);   // lane < 61

    // TOTAL_ROWS is even; base is even; r1 = base+1 always valid.
    for (int base = waveId * 2; base < TOTAL_ROWS; base += nWaves * 2) {
        const floatx4* p0 = (const floatx4*)(cls + (size_t)base * C_DIM);
        const floatx4* p1 = (const floatx4*)(cls + (size_t)(base + 1) * C_DIM);

        // Issue all 4 loads up-front (independent, in flight together).
        floatx4 q00 = __builtin_nontemporal_load(p0 + lane);
        floatx4 q10 = __builtin_nontemporal_load(p1 + lane);
        floatx4 q01 = {0,0,0,0}, q11 = {0,0,0,0};
        if (tail) {
            q01 = __builtin_nontemporal_load(p0 + lane + 64);
            q11 = __builtin_nontemporal_load(p1 + lane + 64);
        }

        // Lane-local argmax (strict > keeps first occurrence; chunk0 scanned
        // first so ties within a lane prefer the smaller index).
        float loc0 = -1.0f, loc1 = -1.0f;
        int   bidx0 = 0,    bidx1 = 0;
        scan4(q00, 4 * lane, loc0, bidx0);
        scan4(q10, 4 * lane, loc1, bidx1);
        if (tail) {
            scan4(q01, 4 * (lane + 64), loc0, bidx0);
            scan4(q11, 4 * (lane + 64), loc1, bidx1);
        }

        // Value-only butterflies (interleaved -> ILP on the DS pipe).
        float w0 = loc0, w1 = loc1;
        #pragma unroll
        for (int off = 32; off > 0; off >>= 1) {
            w0 = fmaxf(w0, __shfl_xor(w0, off, 64));
            w1 = fmaxf(w1, __shfl_xor(w1, off, 64));
        }

        // Argmax resolve: prefer chunk-0 candidates (idx<256); within a chunk
        // idx is monotonic in lane, so lowest set lane = smallest index.
        unsigned long long c0a = __ballot(loc0 == w0 && bidx0 < 256);
        unsigned long long c0  = c0a ? c0a : __ballot(loc0 == w0);
        unsigned long long c1a = __ballot(loc1 == w1 && bidx1 < 256);
        unsigned long long c1  = c1a ? c1a : __ballot(loc1 == w1);
        int idx0 = __shfl(bidx0, (int)__builtin_ctzll(c0), 64);
        int idx1 = __shfl(bidx1, (int)__builtin_ctzll(c1), 64);

        // Epilogue: lane 0 -> row base, lane 1 -> row base+1.
        if (lane < 2) {
            const int   row  = base + lane;
            const float best = lane ? w1 : w0;
            const int   bidx = lane ? idx1 : idx0;

            const int n = row % N_DIM;
            float4 a = ((const float4*)anchors)[n];
            float4 r = ((const float4*)reg)[row];

            float width  = a.z - a.x;
            float height = a.w - a.y;
            float ctrx   = a.x + 0.5f * width;
            float ctry   = a.y + 0.5f * height;

            float px = ctrx + (r.x * rf0) * width;
            float py = ctry + (r.y * rf1) * height;
            float pw = expf(r.z * rf2) * width;
            float ph = expf(r.w * rf3) * height;

            float x1 = fminf(fmaxf(px - 0.5f * pw, 0.0f), IMG_W);
            float y1 = fminf(fmaxf(py - 0.5f * ph, 0.0f), IMG_H);
            float x2 = fminf(fmaxf(px + 0.5f * pw, 0.0f), IMG_W);
            float y2 = fminf(fmaxf(py + 0.5f * ph, 0.0f), IMG_H);

            const float m = (best > thresh) ? 1.0f : 0.0f;

            float4 box;
            box.x = x1 * m; box.y = y1 * m; box.z = x2 * m; box.w = y2 * m;
            ((float4*)outBoxes)[row] = box;
            outCls[row]   = m != 0.0f ? (float)bidx : 0.0f;
            outScore[row] = best * m;
            outMask[row]  = m;
        }
    }
}

extern "C" void kernel_launch(void* const* d_in, const int* in_sizes, int n_in,
                              void* d_out, int out_size, void* d_ws, size_t ws_size,
                              hipStream_t stream) {
    // Input order per setup_inputs(): imgs, classifications, regressions,
    // anchors, cls_thresh, regress_factor.
    const float* cls     = (const float*)d_in[1];
    const float* reg     = (const float*)d_in[2];
    const float* anchors = (const float*)d_in[3];
    const float* thresh  = (const float*)d_in[4];
    const float* rfac    = (const float*)d_in[5];
    float* out = (float*)d_out;

    const int block = 256;   // 4 waves/block
    const int grid  = 2048;  // 8192 waves; 2 rows per wave-iteration

    InferenceTransform_66202625900988_kernel<<<grid, block, 0, stream>>>(
        cls, reg, anchors, thresh, rfac, out);
}

// Round 4
// 155.332 us; speedup vs baseline: 1.1597x; 1.0272x over previous
//
#include <hip/hip_runtime.h>

// Problem constants (from reference): B=4, N=100000, C=500, H=W=512.
#define B_DIM 4
#define N_DIM 100000
#define C_DIM 500
#define TOTAL_ROWS (B_DIM * N_DIM)
#define IMG_W 512.0f
#define IMG_H 512.0f

// Native clang vector type: accepted by __builtin_nontemporal_load.
typedef float floatx4 __attribute__((ext_vector_type(4)));

// 500 floats = 125 float4 per row. Lane l covers vec l (chunk 0) and vec l+64
// (chunk 1, lanes 0..60 only). Global idx = 4*(lane + 64*chunk) + j, monotonic
// in lane within a chunk -> ballot-based argmax tie-break is exact.

__device__ __forceinline__ void scan4(floatx4 q, int i0, float& best, int& bidx) {
    if (q.x > best) { best = q.x; bidx = i0;     }
    if (q.y > best) { best = q.y; bidx = i0 + 1; }
    if (q.z > best) { best = q.z; bidx = i0 + 2; }
    if (q.w > best) { best = q.w; bidx = i0 + 3; }
}

__global__ __launch_bounds__(256) void InferenceTransform_66202625900988_kernel(
    const float* __restrict__ cls,       // [B,N,C]
    const float* __restrict__ reg,       // [B,N,4]
    const float* __restrict__ anchors,   // [1,N,4]
    const float* __restrict__ thresh_p,  // [1]
    const float* __restrict__ rfac,      // [4]
    float* __restrict__ out)             // boxes[B*N*4] | cls[B*N] | scores[B*N] | mask[B*N]
{
    const int lane          = threadIdx.x & 63;
    const int waveInBlock   = threadIdx.x >> 6;
    const int wavesPerBlock = blockDim.x >> 6;
    const int waveId        = blockIdx.x * wavesPerBlock + waveInBlock;
    const int nWaves        = gridDim.x * wavesPerBlock;
    const int stride        = nWaves * 2;

    const float thresh = thresh_p[0];
    const float rf0 = rfac[0], rf1 = rfac[1], rf2 = rfac[2], rf3 = rfac[3];

    float*       outBoxes = out;
    float*       outCls   = out + (size_t)TOTAL_ROWS * 4;
    float*       outScore = outCls + (size_t)TOTAL_ROWS;
    float*       outMask  = outScore + (size_t)TOTAL_ROWS;

    const bool tail = lane < (C_DIM / 4 - 64);   // lane < 61
    const bool epi  = lane < 2;

    // Stage loader: 4 nontemporal cls loads + predicated anchors/reg loads.
    #define LOAD_STAGE(b, x00, x10, x01, x11, aa, rr)                          \
        {                                                                      \
            const floatx4* p0 = (const floatx4*)(cls + (size_t)(b) * C_DIM);   \
            const floatx4* p1 = (const floatx4*)(cls + (size_t)((b)+1) * C_DIM);\
            x00 = __builtin_nontemporal_load(p0 + lane);                       \
            x10 = __builtin_nontemporal_load(p1 + lane);                       \
            if (tail) {                                                        \
                x01 = __builtin_nontemporal_load(p0 + lane + 64);              \
                x11 = __builtin_nontemporal_load(p1 + lane + 64);              \
            }                                                                  \
            if (epi) {                                                         \
                int rw = (b) + lane;                                           \
                aa = *(const floatx4*)(anchors + (size_t)(rw % N_DIM) * 4);    \
                rr = *(const floatx4*)(reg + (size_t)rw * 4);                  \
            }                                                                  \
        }

    int base = waveId * 2;   // 8192 waves * 2 = 16384 <= 400000: all waves work
    floatx4 c00, c10, c01 = {0,0,0,0}, c11 = {0,0,0,0}, ca = {0,0,0,0}, cr = {0,0,0,0};
    LOAD_STAGE(base, c00, c10, c01, c11, ca, cr);

    while (true) {
        const int nxt = base + stride;
        const bool has = nxt < TOTAL_ROWS;
        floatx4 n00 = {0,0,0,0}, n10 = {0,0,0,0}, n01 = {0,0,0,0},
                n11 = {0,0,0,0}, na = {0,0,0,0}, nr = {0,0,0,0};
        if (has) LOAD_STAGE(nxt, n00, n10, n01, n11, na, nr);

        // ---- process current batch (rows base, base+1) ----
        float loc0 = -1.0f, loc1 = -1.0f;
        int   bidx0 = 0,    bidx1 = 0;
        scan4(c00, 4 * lane, loc0, bidx0);
        scan4(c10, 4 * lane, loc1, bidx1);
        if (tail) {
            scan4(c01, 4 * (lane + 64), loc0, bidx0);
            scan4(c11, 4 * (lane + 64), loc1, bidx1);
        }

        float w0 = loc0, w1 = loc1;
        #pragma unroll
        for (int off = 32; off > 0; off >>= 1) {
            w0 = fmaxf(w0, __shfl_xor(w0, off, 64));
            w1 = fmaxf(w1, __shfl_xor(w1, off, 64));
        }

        unsigned long long c0a = __ballot(loc0 == w0 && bidx0 < 256);
        unsigned long long c0  = c0a ? c0a : __ballot(loc0 == w0);
        unsigned long long c1a = __ballot(loc1 == w1 && bidx1 < 256);
        unsigned long long c1  = c1a ? c1a : __ballot(loc1 == w1);
        int idx0 = __shfl(bidx0, (int)__builtin_ctzll(c0), 64);
        int idx1 = __shfl(bidx1, (int)__builtin_ctzll(c1), 64);

        if (epi) {
            const int   row  = base + lane;
            const float best = lane ? w1 : w0;
            const int   bidx = lane ? idx1 : idx0;

            float width  = ca.z - ca.x;
            float height = ca.w - ca.y;
            float ctrx   = ca.x + 0.5f * width;
            float ctry   = ca.y + 0.5f * height;

            float px = ctrx + (cr.x * rf0) * width;
            float py = ctry + (cr.y * rf1) * height;
            float pw = __expf(cr.z * rf2) * width;
            float ph = __expf(cr.w * rf3) * height;

            float x1 = fminf(fmaxf(px - 0.5f * pw, 0.0f), IMG_W);
            float y1 = fminf(fmaxf(py - 0.5f * ph, 0.0f), IMG_H);
            float x2 = fminf(fmaxf(px + 0.5f * pw, 0.0f), IMG_W);
            float y2 = fminf(fmaxf(py + 0.5f * ph, 0.0f), IMG_H);

            const float m = (best > thresh) ? 1.0f : 0.0f;

            floatx4 box;
            box.x = x1 * m; box.y = y1 * m; box.z = x2 * m; box.w = y2 * m;
            *(floatx4*)(outBoxes + (size_t)row * 4) = box;
            outCls[row]   = m != 0.0f ? (float)bidx : 0.0f;
            outScore[row] = best * m;
            outMask[row]  = m;
        }

        if (!has) break;
        base = nxt;
        c00 = n00; c10 = n10; c01 = n01; c11 = n11; ca = na; cr = nr;
    }
    #undef LOAD_STAGE
}

extern "C" void kernel_launch(void* const* d_in, const int* in_sizes, int n_in,
                              void* d_out, int out_size, void* d_ws, size_t ws_size,
                              hipStream_t stream) {
    // Input order per setup_inputs(): imgs, classifications, regressions,
    // anchors, cls_thresh, regress_factor.
    const float* cls     = (const float*)d_in[1];
    const float* reg     = (const float*)d_in[2];
    const float* anchors = (const float*)d_in[3];
    const float* thresh  = (const float*)d_in[4];
    const float* rfac    = (const float*)d_in[5];
    float* out = (float*)d_out;

    const int block = 256;   // 4 waves/block
    const int grid  = 2048;  // 8192 waves; 2 rows/wave-iter, pipelined depth-1

    InferenceTransform_66202625900988_kernel<<<grid, block, 0, stream>>>(
        cls, reg, anchors, thresh, rfac, out);
}

// Round 5
// 154.507 us; speedup vs baseline: 1.1658x; 1.0053x over previous
//
#include <hip/hip_runtime.h>

// Problem constants (from reference): B=4, N=100000, C=500, H=W=512.
#define B_DIM 4
#define N_DIM 100000
#define C_DIM 500
#define TOTAL_ROWS (B_DIM * N_DIM)   // 400000
#define NBATCH (TOTAL_ROWS / 2)      // 200000 (2 rows per batch)
#define IMG_W 512.0f
#define IMG_H 512.0f

// Native clang vector type: accepted by __builtin_nontemporal_load.
typedef float floatx4 __attribute__((ext_vector_type(4)));

// 500 floats = 125 float4/row. Lane l covers vec l (chunk 0) and vec
// min(l+64,124) (chunk 1; lanes 61-63 duplicate vec 124 with its TRUE index,
// so the lowest-lane ballot tie-break still returns the first occurrence).
//
// All memory ops in the loop body are UNCONDITIONAL (addresses clamped, never
// branched) so SIInsertWaitcnts sees identical scoreboard state on every path
// and emits counted vmcnt waits -> the depth-1 prefetch actually overlaps.

__device__ __forceinline__ void scan4(floatx4 q, int i0, float& best, int& bidx) {
    if (q.x > best) { best = q.x; bidx = i0;     }
    if (q.y > best) { best = q.y; bidx = i0 + 1; }
    if (q.z > best) { best = q.z; bidx = i0 + 2; }
    if (q.w > best) { best = q.w; bidx = i0 + 3; }
}

struct Stage {
    floatx4 q00, q10, q01, q11;  // cls: (row0,row1) x (chunk0,chunk1)
    floatx4 a, r;                // anchors / regressions for row base+lidx
};

__device__ __forceinline__ Stage load_stage(
    const float* __restrict__ cls, const float* __restrict__ anchors,
    const float* __restrict__ reg, int batch, int lane, int v1, int lidx)
{
    Stage s;
    const int base = batch * 2;
    const floatx4* p0 = (const floatx4*)(cls + (size_t)base * C_DIM);
    const floatx4* p1 = (const floatx4*)(cls + (size_t)(base + 1) * C_DIM);
    s.q00 = __builtin_nontemporal_load(p0 + lane);
    s.q10 = __builtin_nontemporal_load(p1 + lane);
    s.q01 = __builtin_nontemporal_load(p0 + v1);
    s.q11 = __builtin_nontemporal_load(p1 + v1);
    const int rw = base + lidx;
    s.a = *(const floatx4*)(anchors + (size_t)(rw % N_DIM) * 4);
    s.r = *(const floatx4*)(reg + (size_t)rw * 4);
    return s;
}

__global__ __launch_bounds__(256) void InferenceTransform_66202625900988_kernel(
    const float* __restrict__ cls,       // [B,N,C]
    const float* __restrict__ reg,       // [B,N,4]
    const float* __restrict__ anchors,   // [1,N,4]
    const float* __restrict__ thresh_p,  // [1]
    const float* __restrict__ rfac,      // [4]
    float* __restrict__ out)             // boxes[B*N*4] | cls[B*N] | scores[B*N] | mask[B*N]
{
    const int lane          = threadIdx.x & 63;
    const int waveInBlock   = threadIdx.x >> 6;
    const int wavesPerBlock = blockDim.x >> 6;
    const int waveId        = blockIdx.x * wavesPerBlock + waveInBlock;
    const int nWaves        = gridDim.x * wavesPerBlock;

    const int v1   = (lane + 64 < C_DIM / 4) ? (lane + 64) : (C_DIM / 4 - 1);
    const int lidx = (lane < 2) ? lane : 1;   // lanes >=2 replicate lane 1

    const float thresh = thresh_p[0];
    const float rf0 = rfac[0], rf1 = rfac[1], rf2 = rfac[2], rf3 = rfac[3];

    float*       outBoxes = out;
    float*       outCls   = out + (size_t)TOTAL_ROWS * 4;
    float*       outScore = outCls + (size_t)TOTAL_ROWS;
    float*       outMask  = outScore + (size_t)TOTAL_ROWS;

    int batch = waveId;   // 8192 waves <= 200000 batches: all waves have work
    Stage cur = load_stage(cls, anchors, reg, batch, lane, v1, lidx);

    while (true) {
        const int nb = batch + nWaves;
        // Clamped (never branched) prefetch: final iteration prefetches batch
        // 0 -- all waves share those 4 KB, L2 absorbs it.
        const int pb = (nb < NBATCH) ? nb : 0;
        Stage nxt = load_stage(cls, anchors, reg, pb, lane, v1, lidx);

        // ---- process current batch (rows base, base+1) ----
        const int base = batch * 2;
        float loc0 = -1.0f, loc1 = -1.0f;
        int   bidx0 = 0,    bidx1 = 0;
        scan4(cur.q00, 4 * lane, loc0, bidx0);
        scan4(cur.q10, 4 * lane, loc1, bidx1);
        scan4(cur.q01, 4 * v1,   loc0, bidx0);   // dup lanes carry true idx
        scan4(cur.q11, 4 * v1,   loc1, bidx1);

        float w0 = loc0, w1 = loc1;
        #pragma unroll
        for (int off = 32; off > 0; off >>= 1) {
            w0 = fmaxf(w0, __shfl_xor(w0, off, 64));
            w1 = fmaxf(w1, __shfl_xor(w1, off, 64));
        }

        // Argmax: prefer chunk-0 (idx<256) candidates; idx monotone (non-
        // decreasing) in lane within a chunk -> lowest set lane = first idx.
        unsigned long long c0a = __ballot(loc0 == w0 && bidx0 < 256);
        unsigned long long c0  = c0a ? c0a : __ballot(loc0 == w0);
        unsigned long long c1a = __ballot(loc1 == w1 && bidx1 < 256);
        unsigned long long c1  = c1a ? c1a : __ballot(loc1 == w1);
        int idx0 = __shfl(bidx0, (int)__builtin_ctzll(c0), 64);
        int idx1 = __shfl(bidx1, (int)__builtin_ctzll(c1), 64);

        // ---- epilogue on ALL lanes (lanes>=2 exactly replicate lane 1;
        // duplicate-address stores coalesce to one cacheline) ----
        {
            const int   row  = base + lidx;
            const float best = lidx ? w1 : w0;
            const int   bidx = lidx ? idx1 : idx0;

            float width  = cur.a.z - cur.a.x;
            float height = cur.a.w - cur.a.y;
            float ctrx   = cur.a.x + 0.5f * width;
            float ctry   = cur.a.y + 0.5f * height;

            float px = ctrx + (cur.r.x * rf0) * width;
            float py = ctry + (cur.r.y * rf1) * height;
            float pw = __expf(cur.r.z * rf2) * width;
            float ph = __expf(cur.r.w * rf3) * height;

            float x1 = fminf(fmaxf(px - 0.5f * pw, 0.0f), IMG_W);
            float y1 = fminf(fmaxf(py - 0.5f * ph, 0.0f), IMG_H);
            float x2 = fminf(fmaxf(px + 0.5f * pw, 0.0f), IMG_W);
            float y2 = fminf(fmaxf(py + 0.5f * ph, 0.0f), IMG_H);

            const float m = (best > thresh) ? 1.0f : 0.0f;

            floatx4 box;
            box.x = x1 * m; box.y = y1 * m; box.z = x2 * m; box.w = y2 * m;
            *(floatx4*)(outBoxes + (size_t)row * 4) = box;
            outCls[row]   = m != 0.0f ? (float)bidx : 0.0f;
            outScore[row] = best * m;
            outMask[row]  = m;
        }

        if (nb >= NBATCH) break;
        batch = nb;
        cur = nxt;
    }
}

extern "C" void kernel_launch(void* const* d_in, const int* in_sizes, int n_in,
                              void* d_out, int out_size, void* d_ws, size_t ws_size,
                              hipStream_t stream) {
    // Input order per setup_inputs(): imgs, classifications, regressions,
    // anchors, cls_thresh, regress_factor.
    const float* cls     = (const float*)d_in[1];
    const float* reg     = (const float*)d_in[2];
    const float* anchors = (const float*)d_in[3];
    const float* thresh  = (const float*)d_in[4];
    const float* rfac    = (const float*)d_in[5];
    float* out = (float*)d_out;

    const int block = 256;   // 4 waves/block
    const int grid  = 2048;  // 8192 waves; 2 rows/wave-iter, branchless pipeline

    InferenceTransform_66202625900988_kernel<<<grid, block, 0, stream>>>(
        cls, reg, anchors, thresh, rfac, out);
}